// Round 10
// baseline (78.672 us; speedup 1.0000x reference)
//
#include <hip/hip_runtime.h>
#include <math.h>

#define HGT 224
#define WID 224
#define NPIX (HGT * WID)
#define SIGMA 0.0003f
#define EPSV 1e-10f
// margin: beyond sqrt(12.8*SIGMA)=0.062 from the triangle, pr < 2.8e-6;
// dropping such faces changes improb by < 256*2.8e-6 ~ 7e-4 << 2e-2 threshold.
#define MARGIN 0.062f
// 8x8 tile: pixel centers span +/-3.5 px from tile center; pitch 2/224
#define HALFDIAG 0.04420f
#define BAND (MARGIN + HALFDIAG)
// fully-inside margin: 1e-4 of Euclidean distance >> f32 rounding of lam
#define HD_IN (HALFDIAG + 1.0e-4f)

__device__ __forceinline__ float seg_d2(float px, float py, float ax, float ay,
                                        float ex, float ey, float inv) {
    float pax = px - ax, pay = py - ay;
    float t = (pax * ex + pay * ey) * inv;
    t = fminf(fmaxf(t, 0.0f), 1.0f);
    float ddx = pax - t * ex;
    float ddy = pay - t * ey;
    return ddx * ddx + ddy * ddy;
}

// Single fused kernel. 256 threads = 4 waves, one 8x8 pixel tile per block.
// Wave w owns faces [w*chunk, w*chunk+chunk), chunk = ceil(F/4) <= 64.
// Phase 1: lane l builds face (fbeg+l)'s record in registers; tile-0 blocks
//   also write normal1.
// Phase 2: classify vs wave-uniform tile bounds:
//   fully-inside: zpix argmax via 3 shuffles (origin-anchored z affine is
//     safe here — slivers can't fully contain a tile, so coeffs are moderate);
//   boundary: exact lam/seg_d2/exp body fed by shuffles. zpix ANCHORED at
//     vertex 2 (zgx*dx2+zgy*dy2+z2): origin-anchored form loses ~0.5 abs for
//     sliver faces (zgx~1e6 catastrophic cancellation) — caused R9's failure.
// Phase 3: winner color resolved in-wave, 5-float LDS reduction across waves.
__global__ __launch_bounds__(256) void render(
        const float* __restrict__ points,
        const int*   __restrict__ faces,
        const float* __restrict__ rot,
        const float* __restrict__ pos,
        const float* __restrict__ proj,
        const float* __restrict__ colors,
        float* __restrict__ out,
        float* __restrict__ out_normal,
        int B, int P, int F) {
    const int tiles_x = WID / 8;                     // 28
    const int tiles_per_batch = tiles_x * (HGT / 8); // 784
    int b = blockIdx.x / tiles_per_batch;
    int tile = blockIdx.x - b * tiles_per_batch;
    int ty = tile / tiles_x;
    int tx = tile - ty * tiles_x;

    int t = threadIdx.x & 63;
    int w = threadIdx.x >> 6;
    int lx = t & 7, ly = t >> 3;
    int xx = tx * 8 + lx;
    int yy = ty * 8 + ly;
    float px = (2.0f * (float)xx + 1.0f) / (float)WID - 1.0f;
    float py = 1.0f - (2.0f * (float)yy + 1.0f) / (float)HGT;

    // wave-uniform tile bounds (+ margin) and tile center
    float txlo = (2.0f * (float)(tx * 8) + 1.0f) / (float)WID - 1.0f - MARGIN;
    float txhi = (2.0f * (float)(tx * 8 + 7) + 1.0f) / (float)WID - 1.0f + MARGIN;
    float tyhi = 1.0f - (2.0f * (float)(ty * 8) + 1.0f) / (float)HGT + MARGIN;
    float tylo = 1.0f - (2.0f * (float)(ty * 8 + 7) + 1.0f) / (float)HGT - MARGIN;
    float cx = (16.0f * (float)tx + 8.0f) / (float)WID - 1.0f;
    float cy = 1.0f - (16.0f * (float)ty + 8.0f) / (float)HGT;

    int chunk = (F + 3) >> 2;       // <= 64 required (F <= 256)
    int fbeg = w * chunk;
    int fend = min(fbeg + chunk, F);
    int fl = fbeg + t;
    bool valid = fl < fend;

    // ---- phase 1: per-lane face build (face fl) ----
    float x0 = 0, y0 = 0, x1 = 0, y1 = 0, x2 = 0, y2 = 0;
    float a00 = 0, a01 = 0, a10 = 0, a11 = 0;
    float zgx = 0, zgy = 0, zc = 0, z2r = 0;
    float e01x = 0, e01y = 0, i01 = 0;
    float e12x = 0, e12y = 0, i12 = 0;
    float e20x = 0, e20y = 0, i20 = 0;
    bool pass = false, incl = false;
    if (valid) {
        const float* Rb = rot + b * 9;
        float posx = pos[b * 3 + 0], posy = pos[b * 3 + 1], posz = pos[b * 3 + 2];
        float pj0 = proj[0], pj1 = proj[1], pj2 = proj[2];
        float pcx[3], pcy[3], pcz[3], qx[3], qy[3];
        #pragma unroll
        for (int v = 0; v < 3; v++) {
            int i = faces[fl * 3 + v];
            float dx = points[(b * P + i) * 3 + 0] - posx;
            float dy = points[(b * P + i) * 3 + 1] - posy;
            float dz = points[(b * P + i) * 3 + 2] - posz;
            pcx[v] = Rb[0] * dx + Rb[1] * dy + Rb[2] * dz;
            pcy[v] = Rb[3] * dx + Rb[4] * dy + Rb[5] * dz;
            pcz[v] = Rb[6] * dx + Rb[7] * dy + Rb[8] * dz;
            float zz = pcz[v] * pj2;
            qx[v] = (pcx[v] * pj0) / zz;
            qy[v] = (pcy[v] * pj1) / zz;
        }
        float ux = pcx[1] - pcx[0], uy = pcy[1] - pcy[0], uz = pcz[1] - pcz[0];
        float vx = pcx[2] - pcx[0], vy = pcy[2] - pcy[0], vz = pcz[2] - pcz[0];
        float nx = uy * vz - uz * vy;
        float ny = uz * vx - ux * vz;
        float nz = ux * vy - uy * vx;
        float ninv = 1.0f / sqrtf(nx * nx + ny * ny + nz * nz + EPSV);
        if (tile == 0) {            // one block per batch writes normal1
            out_normal[(b * F + fl) * 3 + 0] = nx * ninv;
            out_normal[(b * F + fl) * 3 + 1] = ny * ninv;
            out_normal[(b * F + fl) * 3 + 2] = nz * ninv;
        }
        x0 = qx[0]; y0 = qy[0]; x1 = qx[1]; y1 = qy[1]; x2 = qx[2]; y2 = qy[2];
        float denom = (y1 - y2) * (x0 - x2) + (x2 - x1) * (y0 - y2);
        if (fabsf(denom) < EPSV) denom = EPSV;
        float rd = 1.0f / denom;
        a00 = (y1 - y2) * rd;
        a01 = (x2 - x1) * rd;
        a10 = (y2 - y0) * rd;
        a11 = (x0 - x2) * rd;
        float z0 = pcz[0], z1 = pcz[1];
        z2r = pcz[2];
        zgx = a00 * (z0 - z2r) + a10 * (z1 - z2r);
        zgy = a01 * (z0 - z2r) + a11 * (z1 - z2r);
        zc  = z2r - zgx * x2 - zgy * y2;
        e01x = x1 - x0; e01y = y1 - y0; i01 = 1.0f / (e01x * e01x + e01y * e01y + EPSV);
        e12x = x2 - x1; e12y = y2 - y1; i12 = 1.0f / (e12x * e12x + e12y * e12y + EPSV);
        e20x = x0 - x2; e20y = y0 - y2; i20 = 1.0f / (e20x * e20x + e20y * e20y + EPSV);

        bool front = nz > 0.0f;
        if (front) {
            float bxmin = fminf(x0, fminf(x1, x2));
            float bymin = fminf(y0, fminf(y1, y2));
            float bxmax = fmaxf(x0, fmaxf(x1, x2));
            float bymax = fmaxf(y0, fmaxf(y1, y2));
            bool bpass = (bxmin <= txhi) & (bxmax >= txlo) & (bymin <= tyhi) & (bymax >= tylo);
            // signed Euclidean dist to edge-line i at tile center (>0 inside);
            // degenerate faces: grad ~ 0 -> dist ~ 0 -> boundary class (safe)
            float n0 = 1.0f / sqrtf(a00 * a00 + a01 * a01 + EPSV);
            float n1 = 1.0f / sqrtf(a10 * a10 + a11 * a11 + EPSV);
            float g2x = -(a00 + a10), g2y = -(a01 + a11);
            float n2 = 1.0f / sqrtf(g2x * g2x + g2y * g2y + EPSV);
            float d0 = (a00 * (cx - x2) + a01 * (cy - y2)) * n0;
            float d1 = (a10 * (cx - x2) + a11 * (cy - y2)) * n1;
            float d2 = (1.0f + g2x * (cx - x2) + g2y * (cy - y2)) * n2;
            float dmin = fminf(d0, fminf(d1, d2));
            pass = bpass & (dmin >= -BAND);
            incl = bpass & (dmin >= HD_IN);
        }
    }

    unsigned long long mask_in = __ballot(incl);
    unsigned long long mask_bd = __ballot(pass) & ~mask_in;

    float best = -1e10f;
    int bidx = -1;
    int nin = (int)__popcll(mask_in);

    // ---- fully-inside faces: 3 shuffles + zpix argmax ----
    while (mask_in) {
        int fo = (int)__builtin_ctzll(mask_in);
        mask_in &= mask_in - 1;
        float zx = __shfl(zgx, fo);
        float zy = __shfl(zgy, fo);
        float zk = __shfl(zc,  fo);
        float zpix = zx * px + zy * py + zk;
        if (zpix > best) { best = zpix; bidx = fbeg + fo; }
    }

    // ---- boundary faces: exact body fed by shuffles, no memory ----
    float prod = 1.0f;
    while (mask_bd) {
        int fo = (int)__builtin_ctzll(mask_bd);
        mask_bd &= mask_bd - 1;
        float X2 = __shfl(x2, fo), Y2 = __shfl(y2, fo);
        float A00 = __shfl(a00, fo), A01 = __shfl(a01, fo);
        float A10 = __shfl(a10, fo), A11 = __shfl(a11, fo);
        float dx2 = px - X2, dy2 = py - Y2;
        float l0 = A00 * dx2 + A01 * dy2;
        float l1 = A10 * dx2 + A11 * dy2;
        float l2 = 1.0f - l0 - l1;
        bool inside = (l0 >= 0.0f) && (l1 >= 0.0f) && (l2 >= 0.0f);

        // z ANCHORED at vertex 2 — origin-anchored form cancels catastrophically
        // for sliver faces (R9 bug)
        float zx = __shfl(zgx, fo), zy = __shfl(zgy, fo), Z2 = __shfl(z2r, fo);
        float zpix = zx * dx2 + zy * dy2 + Z2;
        if (inside && zpix > best) { best = zpix; bidx = fbeg + fo; }

        float X0 = __shfl(x0, fo), Y0 = __shfl(y0, fo);
        float X1 = __shfl(x1, fo), Y1 = __shfl(y1, fo);
        float dA = seg_d2(px, py, X0, Y0, __shfl(e01x, fo), __shfl(e01y, fo), __shfl(i01, fo));
        float dB = seg_d2(px, py, X1, Y1, __shfl(e12x, fo), __shfl(e12y, fo), __shfl(i12, fo));
        float dC = seg_d2(px, py, X2, Y2, __shfl(e20x, fo), __shfl(e20y, fo), __shfl(i20, fo));
        float d2v = inside ? 0.0f : fminf(dA, fminf(dB, dC));
        // pr = exp(-d2/sigma)*(1-1e-7); exp underflow -> pr=0 -> no-op
        float pr = __expf(d2v * (-1.0f / SIGMA)) * (1.0f - 1e-7f);
        prod *= (1.0f - pr);
    }
    // each fully-inside face contributes exactly (1-(1-1e-7f)) = 2^-24:
    // n of them scale prod by 2^(-24n) — bit-identical to n multiplies.
    prod *= exp2f(-24.0f * (float)nin);

    // ---- in-wave winner color (shuffles hoisted so all lanes participate) ----
    float r = 0.0f, g = 0.0f, bcol = 0.0f;
    {
        int wo = (bidx >= 0) ? (bidx - fbeg) : 0;
        float X2 = __shfl(x2, wo), Y2 = __shfl(y2, wo);
        float A00 = __shfl(a00, wo), A01 = __shfl(a01, wo);
        float A10 = __shfl(a10, wo), A11 = __shfl(a11, wo);
        if (bidx >= 0) {
            float dx2 = px - X2, dy2 = py - Y2;
            float l0 = A00 * dx2 + A01 * dy2;
            float l1 = A10 * dx2 + A11 * dy2;
            float l2 = 1.0f - l0 - l1;
            int j0 = faces[bidx * 3 + 0];
            int j1 = faces[bidx * 3 + 1];
            int j2 = faces[bidx * 3 + 2];
            const float* cb = colors + (size_t)b * P * 3;
            r    = l0 * cb[j0 * 3 + 0] + l1 * cb[j1 * 3 + 0] + l2 * cb[j2 * 3 + 0];
            g    = l0 * cb[j0 * 3 + 1] + l1 * cb[j1 * 3 + 1] + l2 * cb[j2 * 3 + 1];
            bcol = l0 * cb[j0 * 3 + 2] + l1 * cb[j1 * 3 + 2] + l2 * cb[j2 * 3 + 2];
        }
    }

    // ---- cross-wave reduction ----
    __shared__ float sc[256], sr[256], sg[256], sb[256], sp[256];
    sc[threadIdx.x] = best;
    sr[threadIdx.x] = r; sg[threadIdx.x] = g; sb[threadIdx.x] = bcol;
    sp[threadIdx.x] = prod;
    __syncthreads();

    if (w == 0) {
        float pb = -1e10f, pprod = 1.0f, rr = 0.0f, gg = 0.0f, bb = 0.0f;
        for (int k = 0; k < 4; k++) {
            int j = k * 64 + t;
            pprod *= sp[j];
            float v = sc[j];
            if (v > pb) {            // ascending wave order => first-max kept
                pb = v; rr = sr[j]; gg = sg[j]; bb = sb[j];
            }
        }
        int pixidx = b * NPIX + yy * WID + xx;
        out[pixidx * 3 + 0] = rr;
        out[pixidx * 3 + 1] = gg;
        out[pixidx * 3 + 2] = bb;
        out[B * NPIX * 3 + pixidx] = 1.0f - pprod;
    }
}

extern "C" void kernel_launch(void* const* d_in, const int* in_sizes, int n_in,
                              void* d_out, int out_size, void* d_ws, size_t ws_size,
                              hipStream_t stream) {
    const float* points = (const float*)d_in[0];
    const int*   faces  = (const int*)d_in[1];
    const float* rot    = (const float*)d_in[2];
    const float* pos    = (const float*)d_in[3];
    const float* proj   = (const float*)d_in[4];
    const float* colors = (const float*)d_in[5];
    float* out = (float*)d_out;

    int F = in_sizes[1] / 3;          // 256
    int B = in_sizes[3] / 3;          // 2
    int P = in_sizes[0] / (3 * B);    // 2048

    float* out_normal = out + B * NPIX * 3 + B * NPIX; // normal1 slice

    int blocks = B * (NPIX / 64);     // one 8x8 tile per block
    render<<<blocks, 256, 0, stream>>>(points, faces, rot, pos, proj, colors,
                                       out, out_normal, B, P, F);
}

// Round 11
// 76.774 us; speedup vs baseline: 1.0247x; 1.0247x over previous
//
#include <hip/hip_runtime.h>
#include <math.h>

#define HGT 224
#define WID 224
#define NPIX (HGT * WID)
#define SIGMA 0.0003f
#define EPSV 1e-10f
#define FILT_STRIDE 16   // floats per face filter record
#define DATA_STRIDE 32   // floats per face data record
// margin: beyond sqrt(12.8*SIGMA)=0.062 from the triangle, pr < 2.8e-6;
// dropping such faces changes improb by < 256*2.8e-6 ~ 7e-4 << 2e-2 threshold.
#define MARGIN 0.062f
// 8x8 tile: pixel centers span +/-3.5 px from tile center; pitch 2/224
#define HALFDIAG 0.04420f
#define BAND (MARGIN + HALFDIAG)
// fully-inside classification margin: 1e-4 >> float eps of the lam math
#define HD_IN (HALFDIAG + 1.0e-4f)

// Filter record (floats, four float4 reads in vectorized prefilter):
//  0-3 : bxmin, bymin, bxmax, bymax   (backface -> inverted inf bbox)
//  4-6 : D0x, D0y, D0c   (signed-dist edge-line 0: D.x*px+D.y*py+D.c, >0 inside)
//  7-9 : D1x, D1y, D1c
// 10-12: D2x, D2y, D2c
// 13-15: zgx, zgy, zc    (zpix = zgx*px + zgy*py + zc — fully-inside fast path;
//        origin-anchored form is safe ONLY for the fully-inside class: slivers
//        (whose zg coeffs explode and cancel) can never fully contain a tile)
//
// Data record v4:
//  0: x2  1: y2  2: zgx  3: zgy  4: z2      (zpix = zgx*dx2 + zgy*dy2 + z2,
//        ANCHORED at vertex 2 — required for sliver faces, see R9 post-mortem)
//  5: a00 6: a01 7: a10  8: a11
//  9: x0 10: y0 11: x1  12: y1
// 13-15: e01x,e01y,inv01  16-18: e12x,e12y,inv12  19-21: e20x,e20y,inv20
// 22-30: c0r,c0g,c0b, c1r,c1g,c1b, c2r,c2g,c2b   31: pad

__global__ void face_pre(const float* __restrict__ points,
                         const int* __restrict__ faces,
                         const float* __restrict__ rot,
                         const float* __restrict__ pos,
                         const float* __restrict__ proj,
                         const float* __restrict__ colors,
                         float* __restrict__ filt,
                         float* __restrict__ data,
                         float* __restrict__ out_normal,
                         int B, int P, int F) {
    int gid = blockIdx.x * blockDim.x + threadIdx.x;
    if (gid >= B * F) return;
    int b = gid / F;
    int f = gid - b * F;

    const float* Rb = rot + b * 9;
    float posx = pos[b * 3 + 0], posy = pos[b * 3 + 1], posz = pos[b * 3 + 2];
    float pj0 = proj[0], pj1 = proj[1], pj2 = proj[2];

    float pcx[3], pcy[3], pcz[3], qx[3], qy[3], col[9];
    for (int v = 0; v < 3; v++) {
        int i = faces[f * 3 + v];
        float dx = points[(b * P + i) * 3 + 0] - posx;
        float dy = points[(b * P + i) * 3 + 1] - posy;
        float dz = points[(b * P + i) * 3 + 2] - posz;
        pcx[v] = Rb[0] * dx + Rb[1] * dy + Rb[2] * dz;
        pcy[v] = Rb[3] * dx + Rb[4] * dy + Rb[5] * dz;
        pcz[v] = Rb[6] * dx + Rb[7] * dy + Rb[8] * dz;
        float zz = pcz[v] * pj2;
        qx[v] = (pcx[v] * pj0) / zz;
        qy[v] = (pcy[v] * pj1) / zz;
        col[v * 3 + 0] = colors[(b * P + i) * 3 + 0];
        col[v * 3 + 1] = colors[(b * P + i) * 3 + 1];
        col[v * 3 + 2] = colors[(b * P + i) * 3 + 2];
    }

    float ux = pcx[1] - pcx[0], uy = pcy[1] - pcy[0], uz = pcz[1] - pcz[0];
    float vx = pcx[2] - pcx[0], vy = pcy[2] - pcy[0], vz = pcz[2] - pcz[0];
    float nx = uy * vz - uz * vy;
    float ny = uz * vx - ux * vz;
    float nz = ux * vy - uy * vx;
    float ninv = 1.0f / sqrtf(nx * nx + ny * ny + nz * nz + EPSV);
    out_normal[gid * 3 + 0] = nx * ninv;
    out_normal[gid * 3 + 1] = ny * ninv;
    out_normal[gid * 3 + 2] = nz * ninv;

    float x0 = qx[0], y0 = qy[0], x1 = qx[1], y1 = qy[1], x2 = qx[2], y2 = qy[2];
    float denom = (y1 - y2) * (x0 - x2) + (x2 - x1) * (y0 - y2);
    if (fabsf(denom) < EPSV) denom = EPSV;
    float rd = 1.0f / denom;

    float a00 = (y1 - y2) * rd;
    float a01 = (x2 - x1) * rd;
    float a10 = (y2 - y0) * rd;
    float a11 = (x0 - x2) * rd;

    float z0 = pcz[0], z1 = pcz[1], z2c = pcz[2];
    float zgx = a00 * (z0 - z2c) + a10 * (z1 - z2c);
    float zgy = a01 * (z0 - z2c) + a11 * (z1 - z2c);
    float zc  = z2c - zgx * x2 - zgy * y2;

    // ---- filter record ----
    float* fq = filt + gid * FILT_STRIDE;
    bool front = nz > 0.0f;
    fq[0] = front ? fminf(x0, fminf(x1, x2)) :  1e30f;
    fq[1] = front ? fminf(y0, fminf(y1, y2)) :  1e30f;
    fq[2] = front ? fmaxf(x0, fmaxf(x1, x2)) : -1e30f;
    fq[3] = front ? fmaxf(y0, fmaxf(y1, y2)) : -1e30f;

    // signed Euclidean dist to edge-line i = lam_i / |grad lam_i| (>0 inside);
    // degenerate faces: grad ~ 0 -> D ~ 0 -> dist 0 -> boundary class (safe)
    float n0 = 1.0f / sqrtf(a00 * a00 + a01 * a01 + EPSV);
    float n1 = 1.0f / sqrtf(a10 * a10 + a11 * a11 + EPSV);
    float g2x = -(a00 + a10), g2y = -(a01 + a11);
    float n2 = 1.0f / sqrtf(g2x * g2x + g2y * g2y + EPSV);
    fq[4] = a00 * n0;
    fq[5] = a01 * n0;
    fq[6] = -(a00 * x2 + a01 * y2) * n0;
    fq[7] = a10 * n1;
    fq[8] = a11 * n1;
    fq[9] = -(a10 * x2 + a11 * y2) * n1;
    fq[10] = g2x * n2;
    fq[11] = g2y * n2;
    fq[12] = (1.0f - g2x * x2 - g2y * y2) * n2;
    fq[13] = zgx; fq[14] = zgy; fq[15] = zc;

    // ---- data record (v4 layout) ----
    float* fp = data + gid * DATA_STRIDE;
    fp[0] = x2; fp[1] = y2;
    fp[2] = zgx; fp[3] = zgy; fp[4] = z2c;
    fp[5] = a00; fp[6] = a01; fp[7] = a10; fp[8] = a11;
    fp[9] = x0; fp[10] = y0; fp[11] = x1; fp[12] = y1;

    float e01x = x1 - x0, e01y = y1 - y0;
    float e12x = x2 - x1, e12y = y2 - y1;
    float e20x = x0 - x2, e20y = y0 - y2;
    fp[13] = e01x; fp[14] = e01y; fp[15] = 1.0f / (e01x * e01x + e01y * e01y + EPSV);
    fp[16] = e12x; fp[17] = e12y; fp[18] = 1.0f / (e12x * e12x + e12y * e12y + EPSV);
    fp[19] = e20x; fp[20] = e20y; fp[21] = 1.0f / (e20x * e20x + e20y * e20y + EPSV);
    for (int k = 0; k < 9; k++) fp[22 + k] = col[k];
    fp[31] = 0.0f;
}

__device__ __forceinline__ float seg_d2(float px, float py, float ax, float ay,
                                        float ex, float ey, float inv) {
    float pax = px - ax, pay = py - ay;
    float t = (pax * ex + pay * ey) * inv;
    t = fminf(fmaxf(t, 0.0f), 1.0f);
    float ddx = pax - t * ex;
    float ddy = pay - t * ey;
    return ddx * ddx + ddy * ddy;
}

// 256 threads = 4 waves, one 8x8 pixel tile per block; wave w handles faces
// [w*64, w*64+64). Vectorized prefilter: lane l loads face base+l's filter
// record (incl. z-affine) and classifies. Fully-inside faces are served
// entirely from registers via cross-lane shuffles (no memory in the loop);
// their prod contribution is exactly 2^-24 each -> one popcount + exp2f.
// Boundary faces run the exact lam/seg_d2/exp body with scalar s_loads.
__global__ __launch_bounds__(256) void rast(const float* __restrict__ filt,
                                            const float* __restrict__ data,
                                            float* __restrict__ out,
                                            int B, int F) {
    const int tiles_x = WID / 8;               // 28
    const int tiles_per_batch = tiles_x * (HGT / 8); // 784
    int b = blockIdx.x / tiles_per_batch;
    int tile = blockIdx.x - b * tiles_per_batch;
    int ty = tile / tiles_x;
    int tx = tile - ty * tiles_x;

    int t = threadIdx.x & 63;
    int w = threadIdx.x >> 6;
    int lx = t & 7, ly = t >> 3;
    int x = tx * 8 + lx;
    int y = ty * 8 + ly;
    float px = (2.0f * (float)x + 1.0f) / (float)WID - 1.0f;
    float py = 1.0f - (2.0f * (float)y + 1.0f) / (float)HGT;

    // wave-uniform tile bounds (+ margin) and tile center
    float txlo = (2.0f * (float)(tx * 8) + 1.0f) / (float)WID - 1.0f - MARGIN;
    float txhi = (2.0f * (float)(tx * 8 + 7) + 1.0f) / (float)WID - 1.0f + MARGIN;
    float tyhi = 1.0f - (2.0f * (float)(ty * 8) + 1.0f) / (float)HGT + MARGIN;
    float tylo = 1.0f - (2.0f * (float)(ty * 8 + 7) + 1.0f) / (float)HGT - MARGIN;
    float cx = (16.0f * (float)tx + 8.0f) / (float)WID - 1.0f;
    float cy = 1.0f - (16.0f * (float)ty + 8.0f) / (float)HGT;

    const float* fltb = filt + (size_t)b * F * FILT_STRIDE;
    const float* datb = data + (size_t)b * F * DATA_STRIDE;

    int chunk = (F + 3) >> 2;
    int fbeg = w * chunk;
    int fend = min(fbeg + chunk, F);

    float best = -1e10f;
    int bidx = -1;
    float prod = 1.0f;
    int n_in = 0;   // count of fully-inside faces (each contributes 2^-24)

    for (int base = fbeg; base < fend; base += 64) {
        // vectorized prefilter: lane t tests face base+t, keeps z-affine in regs
        bool pass = false, inclass = false;
        float zgx = 0.0f, zgy = 0.0f, zc = 0.0f;
        int fl = base + t;
        if (fl < fend) {
            const float* fq = fltb + fl * FILT_STRIDE;
            float4 bb = *(const float4*)fq;
            float4 e0 = *(const float4*)(fq + 4);   // D0x,D0y,D0c,D1x
            float4 e1 = *(const float4*)(fq + 8);   // D1y,D1c,D2x,D2y
            float4 e2 = *(const float4*)(fq + 12);  // D2c,zgx,zgy,zc
            bool bpass = (bb.x <= txhi) & (bb.z >= txlo) & (bb.y <= tyhi) & (bb.w >= tylo);
            float d0 = e0.x * cx + e0.y * cy + e0.z;
            float d1 = e0.w * cx + e1.x * cy + e1.y;
            float d2 = e1.z * cx + e1.w * cy + e2.x;
            float dmin = fminf(d0, fminf(d1, d2));
            pass = bpass & (dmin >= -BAND);
            inclass = bpass & (dmin >= HD_IN);
            zgx = e2.y; zgy = e2.z; zc = e2.w;
        }
        unsigned long long mask_in = __ballot(inclass);
        unsigned long long mask_bd = __ballot(pass) & ~mask_in;

        // ---- fully-inside faces: register-only body via shuffles ----
        n_in += (int)__popcll(mask_in);
        while (mask_in) {
            int fo = (int)__builtin_ctzll(mask_in);
            mask_in &= mask_in - 1;
            float zx = __shfl(zgx, fo);
            float zy = __shfl(zgy, fo);
            float zk = __shfl(zc,  fo);
            float zpix = zx * px + zy * py + zk;
            if (zpix > best) { best = zpix; bidx = base + fo; }
        }

        // ---- boundary faces: exact body, predicated ----
        while (mask_bd) {
            int fo = (int)__builtin_ctzll(mask_bd);
            mask_bd &= mask_bd - 1;
            int fi = base + fo;
            const float* fp = datb + fi * DATA_STRIDE;

            float dx2 = px - fp[0], dy2 = py - fp[1];
            float lam0 = fp[5] * dx2 + fp[6] * dy2;
            float lam1 = fp[7] * dx2 + fp[8] * dy2;
            float lam2 = 1.0f - lam0 - lam1;
            bool inside = (lam0 >= 0.0f) && (lam1 >= 0.0f) && (lam2 >= 0.0f);

            float zpix = fp[2] * dx2 + fp[3] * dy2 + fp[4];
            if (inside && zpix > best) { best = zpix; bidx = fi; }

            float dA = seg_d2(px, py, fp[9],  fp[10], fp[13], fp[14], fp[15]);
            float dB = seg_d2(px, py, fp[11], fp[12], fp[16], fp[17], fp[18]);
            float dC = seg_d2(px, py, fp[0],  fp[1],  fp[19], fp[20], fp[21]);
            float d2 = inside ? 0.0f : fminf(dA, fminf(dB, dC));
            // pr = exp(-d2/sigma)*(1-1e-7); exp underflow -> pr=0 -> no-op
            float pr = __expf(d2 * (-1.0f / SIGMA)) * (1.0f - 1e-7f);
            prod *= (1.0f - pr);
        }
    }

    // fold the inside-face contributions: each is exactly (1-(1-1e-7f)) = 2^-24,
    // so n of them scale prod by 2^(-24n) — bit-identical to n multiplies.
    prod *= exp2f(-24.0f * (float)n_in);

    __shared__ float sc[256], sp[256];
    __shared__ int sidx[256];
    sc[threadIdx.x] = best;
    sp[threadIdx.x] = prod;
    sidx[threadIdx.x] = bidx;
    __syncthreads();

    if (w == 0) {
        best = -1e10f; bidx = -1;
        prod = 1.0f;
        for (int k = 0; k < 4; k++) {
            int j = k * 64 + t;
            prod *= sp[j];
            float v = sc[j];
            if (v > best) {          // ascending chunk order => first-max kept
                best = v; bidx = sidx[j];
            }
        }

        float r = 0.0f, g = 0.0f, bb = 0.0f;
        if (bidx >= 0) {
            // per-lane gather of winner's record; recompute lam exactly as
            // the loop/reference does
            const float* fp = datb + bidx * DATA_STRIDE;
            float dx2 = px - fp[0], dy2 = py - fp[1];
            float lam0 = fp[5] * dx2 + fp[6] * dy2;
            float lam1 = fp[7] * dx2 + fp[8] * dy2;
            float lam2 = 1.0f - lam0 - lam1;
            r  = lam0 * fp[22] + lam1 * fp[25] + lam2 * fp[28];
            g  = lam0 * fp[23] + lam1 * fp[26] + lam2 * fp[29];
            bb = lam0 * fp[24] + lam1 * fp[27] + lam2 * fp[30];
        }

        int pixidx = b * NPIX + y * WID + x;
        out[pixidx * 3 + 0] = r;
        out[pixidx * 3 + 1] = g;
        out[pixidx * 3 + 2] = bb;
        out[B * NPIX * 3 + pixidx] = 1.0f - prod;
    }
}

extern "C" void kernel_launch(void* const* d_in, const int* in_sizes, int n_in,
                              void* d_out, int out_size, void* d_ws, size_t ws_size,
                              hipStream_t stream) {
    const float* points = (const float*)d_in[0];
    const int*   faces  = (const int*)d_in[1];
    const float* rot    = (const float*)d_in[2];
    const float* pos    = (const float*)d_in[3];
    const float* proj   = (const float*)d_in[4];
    const float* colors = (const float*)d_in[5];
    float* out = (float*)d_out;

    int F = in_sizes[1] / 3;          // 256
    int B = in_sizes[3] / 3;          // 2
    int P = in_sizes[0] / (3 * B);    // 2048

    float* filt = (float*)d_ws;                        // B*F*16 floats
    float* data = filt + (size_t)B * F * FILT_STRIDE;  // B*F*32 floats
    float* out_normal = out + B * NPIX * 3 + B * NPIX; // normal1 slice

    int nf = B * F;
    face_pre<<<(nf + 255) / 256, 256, 0, stream>>>(points, faces, rot, pos, proj,
                                                   colors, filt, data, out_normal,
                                                   B, P, F);

    int blocks = B * (NPIX / 64);   // one 8x8 tile per block
    rast<<<blocks, 256, 0, stream>>>(filt, data, out, B, F);
}